// Round 4
// baseline (165.375 us; speedup 1.0000x reference)
//
#include <hip/hip_runtime.h>
#include <math.h>

// Problem constants
#define KS    11
#define H     512
#define W     512
#define OH    502
#define OW    502
#define NPLANES 48
#define TOTAL_OUT (NPLANES * OH * OW)   // 12,096,192

// Full-width 512-thread blocks, TH=4 output rows/iter, 4 signals (xx+yy fused).
// LDS 33.5 KB -> 3 blocks/CU; grid 768 = exactly 3/CU, all resident.
#define TH      4
#define IROWS   (TH + KS - 1)     // 14 input rows per iteration
#define NSIG    4                 // mu_x, mu_y, conv(x^2+y^2), conv(xy)
#define LVW     523               // ODD stride (words), 523 % 32 == 11 -> conflict-free algebra
#define NTHREADS 512
#define CHUNK   32                // output rows per block
#define ITERS   (CHUNK / TH)      // 8
#define NCHUNKS 16                // 16*32 = 512 >= 502

__global__ void zero_out_kernel(float* out) { out[0] = 0.0f; }

// Empirical launch_bounds semantics on this compiler (rounds 1-2): 2nd arg = min BLOCKS/CU.
// (512,3) -> 24 waves/CU -> 85-VGPR budget. Live set ~70 -> no spill.
__global__ __launch_bounds__(NTHREADS, 3) void ssim_kernel(
    const float* __restrict__ x,
    const float* __restrict__ y,
    const float* __restrict__ win,
    float* __restrict__ out)
{
    __shared__ float v[NSIG][TH][LVW];   // 33,472 B -> 3 blocks/CU (24 waves = 75%)
    __shared__ float w1s[KS];
    __shared__ float wsum[NTHREADS / 64];

    const int t     = threadIdx.x;          // == input column
    const int chunk = blockIdx.x;           // 0..15
    const int plane = blockIdx.y;           // 0..47

    const int row_lo = chunk * CHUNK;
    const int row_hi = (row_lo + CHUNK < OH) ? (row_lo + CHUNK) : OH;

    const float* __restrict__ xp = x + (size_t)plane * (H * W);
    const float* __restrict__ yp = y + (size_t)plane * (H * W);

    // Separable taps: window = outer(g,g) => g[i] = sqrt(win[i][i])
    if (t < KS) w1s[t] = sqrtf(win[t * KS + t]);
    __syncthreads();

    float w[KS];
#pragma unroll
    for (int k = 0; k < KS; k++) w[k] = w1s[k];

    // Stage-2 mapping (conflict-free, same algebra class as round 3's measured-zero):
    // 4 rows x 128 runs of 4 px. bank = (11r + 4(u%8) + j) mod 32: r -> 4 residues mod 4,
    // 4u -> 8 classes => all 32 banks, 2 lanes each = free.
    const int r  = t & 3;
    const int c0 = (t >> 2) << 2;            // 0..508; reads words c0..c0+13 <= 521 < 523
    const float c1 = 1e-4f;   // (0.01)^2
    const float c2 = 9e-4f;   // (0.03)^2
    float acc = 0.f;

    for (int it = 0; it < ITERS; ++it) {
        const int gy0 = row_lo + it * TH;
        if (gy0 >= row_hi) break;           // uniform across block

        // ---- Stage 1: issue all global loads first (MLP), then vertical conv ----
        // All input rows 0..511 legal; clamp only feeds outputs >= 502 (discarded by guard).
        float rxv[IROWS], ryv[IROWS];
#pragma unroll
        for (int j = 0; j < IROWS; j++) {
            int gy = gy0 + j; gy = (gy < H - 1) ? gy : (H - 1);
            rxv[j] = xp[gy * W + t];
            ryv[j] = yp[gy * W + t];
        }

        float a0[TH], a1[TH], a2[TH], a3[TH];
#pragma unroll
        for (int q = 0; q < TH; q++) { a0[q]=0.f; a1[q]=0.f; a2[q]=0.f; a3[q]=0.f; }

#pragma unroll
        for (int j = 0; j < IROWS; j++) {
            const float xv = rxv[j], yv = ryv[j];
            const float pss = xv * xv + yv * yv;   // fused x^2+y^2 signal
            const float pxy = xv * yv;
#pragma unroll
            for (int q = 0; q < TH; q++) {
                if (j - q >= 0 && j - q < KS) {    // constant-folds after unroll
                    const float wk = w[j - q];
                    a0[q] += wk * xv;
                    a1[q] += wk * yv;
                    a2[q] += wk * pss;
                    a3[q] += wk * pxy;
                }
            }
        }

        __syncthreads();    // WAR: previous iteration's stage-2 reads of v are done
#pragma unroll
        for (int q = 0; q < TH; q++) {      // lane==col -> stride-1 words -> conflict-free
            v[0][q][t] = a0[q];
            v[1][q][t] = a1[q];
            v[2][q][t] = a2[q];
            v[3][q][t] = a3[q];
        }
        __syncthreads();    // v ready

        // ---- Stage 2: horizontal 11-tap conv over 4-px run + SSIM ----
        float mu[NSIG][TH];
#pragma unroll
        for (int s = 0; s < NSIG; s++) {
            const float* __restrict__ vrow = &v[s][r][c0];
            float vs[IROWS];
#pragma unroll
            for (int j = 0; j < IROWS; j++) vs[j] = vrow[j];   // b32/ds_read2, conflict-free
#pragma unroll
            for (int p = 0; p < TH; p++) {
                float m = 0.f;
#pragma unroll
                for (int k = 0; k < KS; k++) m += w[k] * vs[p + k];
                mu[s][p] = m;
            }
        }

        const int grow  = gy0 + r;
        const bool rowok = (grow < row_hi);
#pragma unroll
        for (int p = 0; p < TH; p++) {
            if (rowok && (c0 + p) < OW) {
                const float mux = mu[0][p], muy = mu[1][p];
                const float mxy = mux * muy;
                const float m2  = mux * mux + muy * muy;
                const float sss = mu[2][p] - m2;        // sigma_x^2 + sigma_y^2
                const float sxy = mu[3][p] - mxy;
                const float num = (2.f * sxy + c2) * (2.f * mxy + c1);
                const float den = (sss + c2) * (m2 + c1);
                acc += num * __builtin_amdgcn_rcpf(den);
            }
        }
    }

    // ---- Reduction: wave shuffle -> cross-wave LDS -> one atomic/block ----
#pragma unroll
    for (int off = 32; off > 0; off >>= 1)
        acc += __shfl_down(acc, off, 64);

    if ((t & 63) == 0) wsum[t >> 6] = acc;
    __syncthreads();
    if (t == 0) {
        float s = 0.f;
#pragma unroll
        for (int i = 0; i < NTHREADS / 64; i++) s += wsum[i];
        atomicAdd(out, s * (1.0f / (float)TOTAL_OUT));
    }
}

extern "C" void kernel_launch(void* const* d_in, const int* in_sizes, int n_in,
                              void* d_out, int out_size, void* d_ws, size_t ws_size,
                              hipStream_t stream)
{
    const float* x   = (const float*)d_in[0];
    const float* y   = (const float*)d_in[1];
    const float* win = (const float*)d_in[2];
    float* out = (float*)d_out;

    zero_out_kernel<<<1, 1, 0, stream>>>(out);

    // 768 blocks = 3/CU x 256 CUs exactly: all blocks resident from t=0, no rounds, no tail.
    dim3 grid(NCHUNKS, NPLANES);
    ssim_kernel<<<grid, NTHREADS, 0, stream>>>(x, y, win, out);
}

// Round 6
// 153.085 us; speedup vs baseline: 1.0803x; 1.0803x over previous
//
#include <hip/hip_runtime.h>
#include <math.h>

// Problem constants
#define KS    11
#define H     512
#define W     512
#define OH    502
#define OW    502
#define NPLANES 48
#define TOTAL_OUT (NPLANES * OH * OW)   // 12,096,192

// Full-width 512-thread blocks, TH=4 output rows/iter, 4 signals (xx+yy fused).
// Register ring-buffer: 14-row window slides by 4 -> only 8 global loads/iter.
#define TH      4
#define IROWS   (TH + KS - 1)     // 14 input rows in the register window
#define NSIG    4                 // mu_x, mu_y, conv(x^2+y^2), conv(xy)
#define LVW     523               // ODD stride (words), 523 % 32 == 11 -> conflict-free algebra
#define NTHREADS 512
#define CHUNK   32                // output rows per block
#define NCHUNKS 16                // 16*32 = 512 >= 502

__global__ void zero_out_kernel(float* out) { out[0] = 0.0f; }

__device__ __forceinline__ float uniform_f(float v) {
    // v is wave-uniform; route through readfirstlane to place it in an SGPR.
    return __int_as_float(__builtin_amdgcn_readfirstlane(__float_as_int(v)));
}

// Empirical launch_bounds semantics (rounds 1-2): 2nd arg = min BLOCKS/CU.
// (512,3) -> 24 waves/CU -> 85-VGPR budget. Live set ~70 -> no spill.
__global__ __launch_bounds__(NTHREADS, 3) void ssim_kernel(
    const float* __restrict__ x,
    const float* __restrict__ y,
    const float* __restrict__ win,
    float* __restrict__ out)
{
    __shared__ float v[NSIG][TH][LVW];   // 33,472 B -> 3 blocks/CU
    __shared__ float w1s[KS];
    __shared__ float wsum[NTHREADS / 64];

    const int t     = threadIdx.x;          // == input column
    const int chunk = blockIdx.x;           // 0..15
    const int plane = blockIdx.y;           // 0..47

    const int row_lo = chunk * CHUNK;
    const int row_hi = (row_lo + CHUNK < OH) ? (row_lo + CHUNK) : OH;
    const int niter  = (row_hi - row_lo + TH - 1) / TH;   // 8 (chunks 0-14), 6 (chunk 15)

    const float* __restrict__ xp = x + (size_t)plane * (H * W);
    const float* __restrict__ yp = y + (size_t)plane * (H * W);

    // Separable taps: window = outer(g,g) => g[i] = sqrt(win[i][i])
    if (t < KS) w1s[t] = sqrtf(win[t * KS + t]);
    __syncthreads();

    // Taps are wave-uniform -> force into SGPRs (saves 11 VGPRs; v_fma takes 1 SGPR src).
    float w[KS];
#pragma unroll
    for (int k = 0; k < KS; k++) w[k] = uniform_f(w1s[k]);

    // Stage-2 mapping (measured conflict-free in r4): 4 rows x 128 runs of 4 px.
    // bank = (11r + 4(u%8) + j) mod 32 -> all 32 banks, 2 lanes each = free.
    const int r  = t & 3;
    const int c0 = (t >> 2) << 2;            // 0..508; reads words c0..c0+13 <= 521 < 523
    const float c1 = 1e-4f;   // (0.01)^2
    const float c2 = 9e-4f;   // (0.03)^2
    float acc = 0.f;

    // ---- Prime the register ring: rows row_lo..row_lo+13 (all <= 493, in range) ----
    float rx[IROWS], ry[IROWS];
#pragma unroll
    for (int j = 0; j < IROWS; j++) {
        int gy = row_lo + j; gy = (gy < H - 1) ? gy : (H - 1);
        rx[j] = xp[gy * W + t];
        ry[j] = yp[gy * W + t];
    }

    for (int it = 0; it < niter; ++it) {
        const int gy0 = row_lo + it * TH;

        // ---- Stage 1: vertical 11-tap conv from the register window ----
        float a0[TH], a1[TH], a2[TH], a3[TH];
#pragma unroll
        for (int q = 0; q < TH; q++) { a0[q]=0.f; a1[q]=0.f; a2[q]=0.f; a3[q]=0.f; }

#pragma unroll
        for (int j = 0; j < IROWS; j++) {
            const float xv = rx[j], yv = ry[j];
            const float pss = xv * xv + yv * yv;   // fused x^2+y^2 signal
            const float pxy = xv * yv;
#pragma unroll
            for (int q = 0; q < TH; q++) {
                if (j - q >= 0 && j - q < KS) {    // constant-folds after unroll
                    const float wk = w[j - q];
                    a0[q] += wk * xv;
                    a1[q] += wk * yv;
                    a2[q] += wk * pss;
                    a3[q] += wk * pxy;
                }
            }
        }

        __syncthreads();    // WAR: previous iteration's stage-2 reads of v are done
#pragma unroll
        for (int q = 0; q < TH; q++) {      // lane==col -> stride-1 words -> conflict-free
            v[0][q][t] = a0[q];
            v[1][q][t] = a1[q];
            v[2][q][t] = a2[q];
            v[3][q][t] = a3[q];
        }
        __syncthreads();    // v ready

        // ---- Slide the ring + prefetch 4 new rows per image (8 loads) ----
        // Issued here; first use is NEXT iteration's vconv -> no barrier in between,
        // so the vmcnt(0)-before-s_barrier drain never exposes these loads.
        if (it + 1 < niter) {
#pragma unroll
            for (int j = 0; j < IROWS - TH; j++) {   // shift window down by TH
                rx[j] = rx[j + TH];
                ry[j] = ry[j + TH];
            }
#pragma unroll
            for (int j = 0; j < TH; j++) {
                int gy = gy0 + IROWS + j;            // rows gy0+14..gy0+17
                gy = (gy < H - 1) ? gy : (H - 1);    // clamp (feeds only discarded rows)
                rx[IROWS - TH + j] = xp[gy * W + t];
                ry[IROWS - TH + j] = yp[gy * W + t];
            }
        }

        // ---- Stage 2: horizontal 11-tap conv over 4-px run + SSIM ----
        float mu[NSIG][TH];
#pragma unroll
        for (int s = 0; s < NSIG; s++) {
            const float* __restrict__ vrow = &v[s][r][c0];
            float vs[IROWS];
#pragma unroll
            for (int j = 0; j < IROWS; j++) vs[j] = vrow[j];   // b32/ds_read2, conflict-free
#pragma unroll
            for (int p = 0; p < TH; p++) {
                float m = 0.f;
#pragma unroll
                for (int k = 0; k < KS; k++) m += w[k] * vs[p + k];
                mu[s][p] = m;
            }
        }

        const int grow  = gy0 + r;
        const bool rowok = (grow < row_hi);
#pragma unroll
        for (int p = 0; p < TH; p++) {
            if (rowok && (c0 + p) < OW) {
                const float mux = mu[0][p], muy = mu[1][p];
                const float mxy = mux * muy;
                const float m2  = mux * mux + muy * muy;
                const float sss = mu[2][p] - m2;        // sigma_x^2 + sigma_y^2
                const float sxy = mu[3][p] - mxy;
                const float num = (2.f * sxy + c2) * (2.f * mxy + c1);
                const float den = (sss + c2) * (m2 + c1);
                acc += num * __builtin_amdgcn_rcpf(den);
            }
        }
    }

    // ---- Reduction: wave shuffle -> cross-wave LDS -> one atomic/block ----
#pragma unroll
    for (int off = 32; off > 0; off >>= 1)
        acc += __shfl_down(acc, off, 64);

    if ((t & 63) == 0) wsum[t >> 6] = acc;
    __syncthreads();
    if (t == 0) {
        float s = 0.f;
#pragma unroll
        for (int i = 0; i < NTHREADS / 64; i++) s += wsum[i];
        atomicAdd(out, s * (1.0f / (float)TOTAL_OUT));
    }
}

extern "C" void kernel_launch(void* const* d_in, const int* in_sizes, int n_in,
                              void* d_out, int out_size, void* d_ws, size_t ws_size,
                              hipStream_t stream)
{
    const float* x   = (const float*)d_in[0];
    const float* y   = (const float*)d_in[1];
    const float* win = (const float*)d_in[2];
    float* out = (float*)d_out;

    zero_out_kernel<<<1, 1, 0, stream>>>(out);

    // 768 blocks = 3/CU x 256 CUs: all resident from t=0, no rounds, no tail.
    dim3 grid(NCHUNKS, NPLANES);
    ssim_kernel<<<grid, NTHREADS, 0, stream>>>(x, y, win, out);
}